// Round 1
// baseline (530.770 us; speedup 1.0000x reference)
//
#include <hip/hip_runtime.h>
#include <math.h>

#define NUM_ENTS   100000
#define HD         128
#define NUM_EDGES  2000000
#define NUM_RELS2  1000
#define RRELU_SLOPE 0.22916666666666666f
#define NBLK 391                 // ceil(100000/256)
#define NPAD (NBLK * 256)        // 100096 padded counter range
#define EQ4  (NUM_EDGES / 4)     // 500000 4-edge chunks
#define EBLK ((EQ4 + 255) / 256) // 1954 blocks for edge-chunk kernels

// setup_kernel section boundaries (exact covers, no remainders)
#define SB_CNT 391               // zero cnt: 391*256 = 100096
#define SB_HB  25000             // prep hb: 25000*4 rows = 100000
#define SB_RB  125               // relpack: 125*256 = 32000 float4 chunks
#define SB_WP  24                // wpack: 24*4 = 96 sub-blocks
#define SB_TOTAL (SB_CNT + SB_HB + SB_RB + SB_WP)   // 25540

typedef __attribute__((ext_vector_type(8))) short bf16x8;
typedef __attribute__((ext_vector_type(4))) float f32x4;

// ---------- bf16 helpers ----------
__device__ __forceinline__ float bf2f(unsigned short h) {
    union { unsigned int u; float f; } v;
    v.u = ((unsigned int)h) << 16;
    return v.f;
}
__device__ __forceinline__ void unpack2(unsigned int u, float& lo, float& hi) {
    union { unsigned int u; float f; } a, b;
    a.u = u << 16;          // low ushort = element c
    b.u = u & 0xffff0000u;  // high ushort = element c+1
    lo = a.f; hi = b.f;
}
__device__ __forceinline__ unsigned short f2bf(float f) {
    union { float f; unsigned int u; } v; v.f = f;
    unsigned int r = 0x7fffu + ((v.u >> 16) & 1u);  // RNE
    return (unsigned short)((v.u + r) >> 16);
}

// ---------- 1. setup: zero cnt | hb = bf16(l2norm(ent)) | rb | Wp ----------
__global__ void __launch_bounds__(256)
setup_kernel(const float* __restrict__ ent, const float* __restrict__ rel,
             const float* __restrict__ Wn, const float* __restrict__ Ws,
             const float* __restrict__ Wt,
             int* __restrict__ cnt, unsigned short* __restrict__ hb,
             unsigned short* __restrict__ rb, unsigned short* __restrict__ Wp) {
    const int bid = blockIdx.x, tid = threadIdx.x;
    if (bid < SB_CNT) {                                   // zero cnt
        cnt[bid * 256 + tid] = 0;
    } else if (bid < SB_CNT + SB_HB) {                    // hb
        const int row = (bid - SB_CNT) * 4 + (tid >> 6);
        const int lane = tid & 63;
        const float2 v = *(const float2*)(ent + (size_t)row * HD + lane * 2);
        float ss = v.x * v.x + v.y * v.y;
        #pragma unroll
        for (int m = 1; m < 64; m <<= 1) ss += __shfl_xor(ss, m, 64);
        const float inv = 1.0f / fmaxf(sqrtf(ss), 1e-12f);
        const unsigned int o = (unsigned int)f2bf(v.x * inv) |
                               ((unsigned int)f2bf(v.y * inv) << 16);
        *(unsigned int*)(hb + (size_t)row * HD + lane * 2) = o;
    } else if (bid < SB_CNT + SB_HB + SB_RB) {            // rb
        const int i = (bid - SB_CNT - SB_HB) * 256 + tid;
        const float4 v = ((const float4*)rel)[i];
        ushort4 o;
        o.x = f2bf(v.x); o.y = f2bf(v.y); o.z = f2bf(v.z); o.w = f2bf(v.w);
        ((ushort4*)rb)[i] = o;
    } else {                                              // Wp
        const int blk = (bid - SB_CNT - SB_HB - SB_RB) * 4 + (tid >> 6);
        const int lane = tid & 63;
        const int w = blk >> 5, rem = blk & 31, t = rem >> 2, kt = rem & 3;
        const float* W = (w == 0) ? Wn : (w == 1) ? Ws : Wt;
        const int n  = t * 16 + (lane & 15);
        const int k0 = kt * 32 + (lane >> 4) * 8;
        unsigned short tmp[8];
        #pragma unroll
        for (int j = 0; j < 8; ++j) tmp[j] = f2bf(W[(size_t)(k0 + j) * HD + n]);
        unsigned short* d = Wp + ((size_t)blk * 64 + lane) * 8;
        *(ushort4*)(d + 0) = make_ushort4(tmp[0], tmp[1], tmp[2], tmp[3]);
        *(ushort4*)(d + 4) = make_ushort4(tmp[4], tmp[5], tmp[6], tmp[7]);
    }
}

// ---------- 2. histogram: count-only, fire-and-forget atomics ----------
__global__ void __launch_bounds__(256)
hist_kernel(const int* __restrict__ dst, int* __restrict__ cnt) {
    const int i = blockIdx.x * 256 + threadIdx.x;
    if (i < EQ4) {
        const int4 d4 = ((const int4*)dst)[i];
        atomicAdd(&cnt[d4.x], 1);
        atomicAdd(&cnt[d4.y], 1);
        atomicAdd(&cnt[d4.z], 1);
        atomicAdd(&cnt[d4.w], 1);
    }
}

__global__ void __launch_bounds__(256)
scan1_kernel(const int* __restrict__ cnt, int* __restrict__ offs, int* __restrict__ bsum) {
    __shared__ int tmp[256];
    const int t = threadIdx.x;
    const int i = blockIdx.x * 256 + t;
    const int v = cnt[i];
    tmp[t] = v;
    __syncthreads();
    #pragma unroll
    for (int d = 1; d < 256; d <<= 1) {
        const int a = (t >= d) ? tmp[t - d] : 0;
        __syncthreads();
        tmp[t] += a;
        __syncthreads();
    }
    offs[i] = tmp[t] - v;
    if (t == 255) bsum[blockIdx.x] = tmp[255];
}

__global__ void __launch_bounds__(512)
scan2_kernel(int* __restrict__ bsum) {
    __shared__ int tmp[512];
    const int t = threadIdx.x;
    const int v = (t < NBLK) ? bsum[t] : 0;
    tmp[t] = v;
    __syncthreads();
    #pragma unroll
    for (int d = 1; d < 512; d <<= 1) {
        const int a = (t >= d) ? tmp[t - d] : 0;
        __syncthreads();
        tmp[t] += a;
        __syncthreads();
    }
    if (t < NBLK) bsum[t] = tmp[t] - v;
}

// scan3: finalize offs AND write cursor copy (into dead cnt array) for permute
__global__ void __launch_bounds__(256)
scan3_kernel(int* __restrict__ offs, const int* __restrict__ bsum, int* __restrict__ cur) {
    const int i = blockIdx.x * 256 + threadIdx.x;
    const int v = offs[i] + bsum[blockIdx.x];
    offs[i] = v;
    cur[i] = v;
}

// ---------- 3. permute: position via cursor atomicAdd, scatter recs ----------
__global__ void __launch_bounds__(256)
permute_kernel(const int* __restrict__ dst, const int* __restrict__ src,
               const int* __restrict__ ety, const float* __restrict__ enorm,
               int* __restrict__ cur, uint2* __restrict__ recs) {
    const int i = blockIdx.x * 256 + threadIdx.x;
    if (i < EQ4) {
        const int4 d4 = ((const int4*)dst)[i];
        const int4 s4 = ((const int4*)src)[i];
        const int4 t4 = ((const int4*)ety)[i];
        const float4 n4 = ((const float4*)enorm)[i];
        const int p0 = atomicAdd(&cur[d4.x], 1);
        const int p1 = atomicAdd(&cur[d4.y], 1);
        const int p2 = atomicAdd(&cur[d4.z], 1);
        const int p3 = atomicAdd(&cur[d4.w], 1);
        recs[p0] = make_uint2((unsigned int)s4.x | ((unsigned int)t4.x << 17), __float_as_uint(n4.x));
        recs[p1] = make_uint2((unsigned int)s4.y | ((unsigned int)t4.y << 17), __float_as_uint(n4.y));
        recs[p2] = make_uint2((unsigned int)s4.z | ((unsigned int)t4.z << 17), __float_as_uint(n4.z));
        recs[p3] = make_uint2((unsigned int)s4.w | ((unsigned int)t4.w << 17), __float_as_uint(n4.w));
    }
}

// ---------- 4. fused gather + MFMA ----------
__device__ __forceinline__ void accum8(float* acc, uint4 hv, uint4 rv, float w) {
    float h0, h1, r0, r1;
    unpack2(hv.x, h0, h1); unpack2(rv.x, r0, r1);
    acc[0] += (h0 + r0) * w; acc[1] += (h1 + r1) * w;
    unpack2(hv.y, h0, h1); unpack2(rv.y, r0, r1);
    acc[2] += (h0 + r0) * w; acc[3] += (h1 + r1) * w;
    unpack2(hv.z, h0, h1); unpack2(rv.z, r0, r1);
    acc[4] += (h0 + r0) * w; acc[5] += (h1 + r1) * w;
    unpack2(hv.w, h0, h1); unpack2(rv.w, r0, r1);
    acc[6] += (h0 + r0) * w; acc[7] += (h1 + r1) * w;
}

// Per block: 64 rows, 4 waves, 16 rows/wave. Wave-local only -> no barriers.
// Each wave: 4 gather batches (4 dsts each, 16 lanes/dst, unroll-4 + recs
// prefetch) -> bf16 LDS tile -> 3-phase MFMA pipeline -> epilogue.
__global__ void __launch_bounds__(256, 4)
gather_mfma(const unsigned short* __restrict__ hb,
            const unsigned short* __restrict__ rb,
            const int* __restrict__ offs,
            const uint2* __restrict__ recs,
            const unsigned short* __restrict__ Wp,
            const float* __restrict__ bias,
            const float* __restrict__ his,
            float* __restrict__ out) {
    __shared__ unsigned short tile[4][16 * 136];   // per-wave 16x128 bf16, pad 8
    const int tid = threadIdx.x;
    const int wv = tid >> 6, lane = tid & 63;
    const int m0 = blockIdx.x * 64 + wv * 16;      // this wave's 16 rows
    if (m0 >= NUM_ENTS) return;                    // 100000 % 16 == 0: exact cover
    const int grp = lane >> 4, sub = lane & 15;    // gather roles
    const int rA = lane & 15, quad = lane >> 4;    // MFMA roles
    unsigned short* T = tile[wv];
    const unsigned short* hbp = hb + sub * 8;
    const unsigned short* rbp = rb + sub * 8;

    // ---- gather phase: 4 batches of 4 dsts (one dst per 16-lane group) ----
    #pragma unroll
    for (int b = 0; b < 4; ++b) {
        const int rloc = b * 4 + grp;
        const int d = m0 + rloc;
        const int beg = offs[d], end = offs[d + 1];
        float acc[8] = {0.f, 0.f, 0.f, 0.f, 0.f, 0.f, 0.f, 0.f};
        int i = beg;
        uint2 rcA[4];
        #pragma unroll
        for (int k = 0; k < 4; ++k) rcA[k] = recs[min(i + k, NUM_EDGES - 1)];
        while (__any(i < end)) {
            uint2 rcB[4];                          // prefetch next iteration's recs
            #pragma unroll
            for (int k = 0; k < 4; ++k) rcB[k] = recs[min(i + 4 + k, NUM_EDGES - 1)];
            uint4 hv[4], rv[4]; float w[4];
            #pragma unroll
            for (int k = 0; k < 4; ++k) {
                w[k] = (i + k) < end ? __uint_as_float(rcA[k].y) : 0.f;
                hv[k] = *(const uint4*)(hbp + (size_t)(rcA[k].x & 0x1FFFFu) * HD);
                rv[k] = *(const uint4*)(rbp + (size_t)(rcA[k].x >> 17) * HD);
            }
            #pragma unroll
            for (int k = 0; k < 4; ++k) accum8(acc, hv[k], rv[k], w[k]);
            #pragma unroll
            for (int k = 0; k < 4; ++k) rcA[k] = rcB[k];
            i += 4;
        }
        unsigned short* dT = T + rloc * 136 + sub * 8;
        *(ushort4*)(dT + 0) = make_ushort4(f2bf(acc[0]), f2bf(acc[1]), f2bf(acc[2]), f2bf(acc[3]));
        *(ushort4*)(dT + 4) = make_ushort4(f2bf(acc[4]), f2bf(acc[5]), f2bf(acc[6]), f2bf(acc[7]));
    }

    // ---- MFMA phase 1: A = S (LDS), B = Wn ; phase 2: A = h_norm (hb), B = Ws
    const bf16x8* WF = (const bf16x8*)Wp;
    f32x4 acc1[8];
    #pragma unroll
    for (int t = 0; t < 8; ++t) acc1[t] = (f32x4)0.f;

    #pragma unroll
    for (int ph = 0; ph < 2; ++ph) {
        bf16x8 a[4];
        if (ph == 0) {
            #pragma unroll
            for (int kt = 0; kt < 4; ++kt)
                a[kt] = *(const bf16x8*)(T + rA * 136 + kt * 32 + quad * 8);
        } else {
            const unsigned short* base = hb + (size_t)(m0 + rA) * HD + quad * 8;
            #pragma unroll
            for (int kt = 0; kt < 4; ++kt)
                a[kt] = *(const bf16x8*)(base + kt * 32);
        }
        #pragma unroll
        for (int t = 0; t < 8; ++t) {
            #pragma unroll
            for (int kt = 0; kt < 4; ++kt) {
                const bf16x8 bfr = WF[(size_t)(ph * 32 + t * 4 + kt) * 64 + lane];
                acc1[t] = __builtin_amdgcn_mfma_f32_16x16x32_bf16(a[kt], bfr, acc1[t], 0, 0, 0);
            }
        }
    }

    // rrelu (C layout: col = t*16 + rA, row = quad*4 + r)
    #pragma unroll
    for (int t = 0; t < 8; ++t)
        #pragma unroll
        for (int r = 0; r < 4; ++r)
            acc1[t][r] = acc1[t][r] >= 0.f ? acc1[t][r] : RRELU_SLOPE * acc1[t][r];

    // transpose hcur C-layout -> A-layout via wave-local LDS (bf16)
    #pragma unroll
    for (int t = 0; t < 8; ++t)
        #pragma unroll
        for (int r = 0; r < 4; ++r)
            T[(quad * 4 + r) * 136 + t * 16 + rA] = f2bf(acc1[t][r]);

    bf16x8 a3[4];
    #pragma unroll
    for (int kt = 0; kt < 4; ++kt)
        a3[kt] = *(const bf16x8*)(T + rA * 136 + kt * 32 + quad * 8);

    // phase 3 + epilogue fused per-t: one gate accumulator live at a time
    #pragma unroll
    for (int t = 0; t < 8; ++t) {
        const float bn = bias[t * 16 + rA];
        f32x4 c2 = (f32x4){bn, bn, bn, bn};
        #pragma unroll
        for (int kt = 0; kt < 4; ++kt) {
            const bf16x8 bfr = WF[(size_t)(64 + t * 4 + kt) * 64 + lane];
            c2 = __builtin_amdgcn_mfma_f32_16x16x32_bf16(a3[kt], bfr, c2, 0, 0, 0);
        }
        const int col = t * 16 + rA;
        #pragma unroll
        for (int r = 0; r < 4; ++r) {
            const size_t row = (size_t)(m0 + quad * 4 + r);
            const float g = 1.f / (1.f + __expf(-c2[r]));
            const float h = his[row * HD + col];
            out[row * HD + col] = g * acc1[t][r] + (1.f - g) * h;
        }
    }
}

// ---------- launch ----------
extern "C" void kernel_launch(void* const* d_in, const int* in_sizes, int n_in,
                              void* d_out, int out_size, void* d_ws, size_t ws_size,
                              hipStream_t stream) {
    const float* ent   = (const float*)d_in[0];
    const float* rel   = (const float*)d_in[1];
    const float* his   = (const float*)d_in[2];
    const float* Wn    = (const float*)d_in[3];
    const float* Ws    = (const float*)d_in[4];
    const float* Wt    = (const float*)d_in[5];
    const float* bias  = (const float*)d_in[6];
    const float* enorm = (const float*)d_in[7];
    const int* src = (const int*)d_in[8];
    const int* dst = (const int*)d_in[9];
    const int* ety = (const int*)d_in[10];
    float* out = (float*)d_out;

    // ws: hb 25.6MB | rb 256KB | Wp 96KB | cnt 400KB | offs 400KB | bsum 2KB |
    //     recs 16MB   (~42.8MB; ws >= 51.6MB)
    char* p = (char*)d_ws;
    unsigned short* hb = (unsigned short*)p;  p += (size_t)NUM_ENTS * HD * 2;
    unsigned short* rb = (unsigned short*)p;  p += (size_t)NUM_RELS2 * HD * 2;
    unsigned short* Wp = (unsigned short*)p;  p += (size_t)96 * 64 * 8 * 2;
    int* cnt  = (int*)p;                      p += (size_t)NPAD * 4;
    int* offs = (int*)p;                      p += (size_t)NPAD * 4;
    int* bsum = (int*)p;                      p += 512 * 4;
    uint2* recs = (uint2*)p;

    setup_kernel<<<SB_TOTAL, 256, 0, stream>>>(ent, rel, Wn, Ws, Wt, cnt, hb, rb, Wp);
    hist_kernel<<<EBLK, 256, 0, stream>>>(dst, cnt);
    scan1_kernel<<<NBLK, 256, 0, stream>>>(cnt, offs, bsum);
    scan2_kernel<<<1, 512, 0, stream>>>(bsum);
    scan3_kernel<<<NBLK, 256, 0, stream>>>(offs, bsum, cnt);   // cnt -> cursor
    permute_kernel<<<EBLK, 256, 0, stream>>>(dst, src, ety, enorm, cnt, recs);
    gather_mfma<<<(NUM_ENTS + 63) / 64, 256, 0, stream>>>(hb, rb, offs, recs, Wp, bias, his, out);
}

// Round 2
// 433.027 us; speedup vs baseline: 1.2257x; 1.2257x over previous
//
#include <hip/hip_runtime.h>
#include <math.h>

#define NUM_ENTS   100000
#define HD         128
#define NUM_EDGES  2000000
#define NUM_RELS2  1000
#define RRELU_SLOPE 0.22916666666666666f
#define NBLK 391                 // ceil(100000/256)
#define NPAD (NBLK * 256)        // 100096 padded counter range
#define EQ4  (NUM_EDGES / 4)     // 500000 4-edge chunks
#define EBLK ((EQ4 + 255) / 256) // 1954 blocks for edge-chunk kernels

// setup_kernel section boundaries (exact covers, no remainders)
#define SB_CNT 391               // zero cnt: 391*256 = 100096
#define SB_HB  25000             // prep hb: 25000*4 rows = 100000
#define SB_RB  125               // relpack: 125*256 = 32000 float4 chunks
#define SB_WP  24                // wpack: 24*4 = 96 sub-blocks
#define SB_TOTAL (SB_CNT + SB_HB + SB_RB + SB_WP)   // 25540

typedef __attribute__((ext_vector_type(8))) short bf16x8;
typedef __attribute__((ext_vector_type(4))) float f32x4;

// ---------- bf16 helpers ----------
__device__ __forceinline__ float bf2f(unsigned short h) {
    union { unsigned int u; float f; } v;
    v.u = ((unsigned int)h) << 16;
    return v.f;
}
__device__ __forceinline__ void unpack2(unsigned int u, float& lo, float& hi) {
    union { unsigned int u; float f; } a, b;
    a.u = u << 16;          // low ushort = element c
    b.u = u & 0xffff0000u;  // high ushort = element c+1
    lo = a.f; hi = b.f;
}
__device__ __forceinline__ unsigned short f2bf(float f) {
    union { float f; unsigned int u; } v; v.f = f;
    unsigned int r = 0x7fffu + ((v.u >> 16) & 1u);  // RNE
    return (unsigned short)((v.u + r) >> 16);
}

// ---------- 1. setup: zero cnt | hb = bf16(l2norm(ent)) | rb | Wp ----------
__global__ void __launch_bounds__(256)
setup_kernel(const float* __restrict__ ent, const float* __restrict__ rel,
             const float* __restrict__ Wn, const float* __restrict__ Ws,
             const float* __restrict__ Wt,
             int* __restrict__ cnt, unsigned short* __restrict__ hb,
             unsigned short* __restrict__ rb, unsigned short* __restrict__ Wp) {
    const int bid = blockIdx.x, tid = threadIdx.x;
    if (bid < SB_CNT) {                                   // zero cnt
        cnt[bid * 256 + tid] = 0;
    } else if (bid < SB_CNT + SB_HB) {                    // hb
        const int row = (bid - SB_CNT) * 4 + (tid >> 6);
        const int lane = tid & 63;
        const float2 v = *(const float2*)(ent + (size_t)row * HD + lane * 2);
        float ss = v.x * v.x + v.y * v.y;
        #pragma unroll
        for (int m = 1; m < 64; m <<= 1) ss += __shfl_xor(ss, m, 64);
        const float inv = 1.0f / fmaxf(sqrtf(ss), 1e-12f);
        const unsigned int o = (unsigned int)f2bf(v.x * inv) |
                               ((unsigned int)f2bf(v.y * inv) << 16);
        *(unsigned int*)(hb + (size_t)row * HD + lane * 2) = o;
    } else if (bid < SB_CNT + SB_HB + SB_RB) {            // rb
        const int i = (bid - SB_CNT - SB_HB) * 256 + tid;
        const float4 v = ((const float4*)rel)[i];
        ushort4 o;
        o.x = f2bf(v.x); o.y = f2bf(v.y); o.z = f2bf(v.z); o.w = f2bf(v.w);
        ((ushort4*)rb)[i] = o;
    } else {                                              // Wp
        const int blk = (bid - SB_CNT - SB_HB - SB_RB) * 4 + (tid >> 6);
        const int lane = tid & 63;
        const int w = blk >> 5, rem = blk & 31, t = rem >> 2, kt = rem & 3;
        const float* W = (w == 0) ? Wn : (w == 1) ? Ws : Wt;
        const int n  = t * 16 + (lane & 15);
        const int k0 = kt * 32 + (lane >> 4) * 8;
        unsigned short tmp[8];
        #pragma unroll
        for (int j = 0; j < 8; ++j) tmp[j] = f2bf(W[(size_t)(k0 + j) * HD + n]);
        unsigned short* d = Wp + ((size_t)blk * 64 + lane) * 8;
        *(ushort4*)(d + 0) = make_ushort4(tmp[0], tmp[1], tmp[2], tmp[3]);
        *(ushort4*)(d + 4) = make_ushort4(tmp[4], tmp[5], tmp[6], tmp[7]);
    }
}

// ---------- 2. histogram + within-bucket position (int4-vectorized) ----------
// Atomic returns live HERE (fire -> store pos, nothing downstream depends on
// them in this kernel). R1 lesson: making the permute scatter address depend
// on an atomic return costs ~110us of latency stall.
__global__ void __launch_bounds__(256)
hist_kernel(const int* __restrict__ dst, int* __restrict__ cnt, int* __restrict__ pos) {
    const int i = blockIdx.x * 256 + threadIdx.x;
    if (i < EQ4) {
        const int4 d4 = ((const int4*)dst)[i];
        int4 p4;
        p4.x = atomicAdd(&cnt[d4.x], 1);
        p4.y = atomicAdd(&cnt[d4.y], 1);
        p4.z = atomicAdd(&cnt[d4.z], 1);
        p4.w = atomicAdd(&cnt[d4.w], 1);
        ((int4*)pos)[i] = p4;          // contiguous 16B store
    }
}

__global__ void __launch_bounds__(256)
scan1_kernel(const int* __restrict__ cnt, int* __restrict__ offs, int* __restrict__ bsum) {
    __shared__ int tmp[256];
    const int t = threadIdx.x;
    const int i = blockIdx.x * 256 + t;
    const int v = cnt[i];
    tmp[t] = v;
    __syncthreads();
    #pragma unroll
    for (int d = 1; d < 256; d <<= 1) {
        const int a = (t >= d) ? tmp[t - d] : 0;
        __syncthreads();
        tmp[t] += a;
        __syncthreads();
    }
    offs[i] = tmp[t] - v;
    if (t == 255) bsum[blockIdx.x] = tmp[255];
}

__global__ void __launch_bounds__(512)
scan2_kernel(int* __restrict__ bsum) {
    __shared__ int tmp[512];
    const int t = threadIdx.x;
    const int v = (t < NBLK) ? bsum[t] : 0;
    tmp[t] = v;
    __syncthreads();
    #pragma unroll
    for (int d = 1; d < 512; d <<= 1) {
        const int a = (t >= d) ? tmp[t - d] : 0;
        __syncthreads();
        tmp[t] += a;
        __syncthreads();
    }
    if (t < NBLK) bsum[t] = tmp[t] - v;
}

__global__ void __launch_bounds__(256)
scan3_kernel(int* __restrict__ offs, const int* __restrict__ bsum) {
    const int i = blockIdx.x * 256 + threadIdx.x;
    offs[i] += bsum[blockIdx.x];
}

// ---------- 3. permute: pure scatter, plain loads only (no atomics) ----------
__global__ void __launch_bounds__(256)
permute_kernel(const int* __restrict__ dst, const int* __restrict__ src,
               const int* __restrict__ ety, const float* __restrict__ enorm,
               const int* __restrict__ offs, const int* __restrict__ pos,
               uint2* __restrict__ recs) {
    const int i = blockIdx.x * 256 + threadIdx.x;
    if (i < EQ4) {
        const int4 d4 = ((const int4*)dst)[i];
        const int4 s4 = ((const int4*)src)[i];
        const int4 t4 = ((const int4*)ety)[i];
        const float4 n4 = ((const float4*)enorm)[i];
        const int4 p4 = ((const int4*)pos)[i];
        recs[offs[d4.x] + p4.x] = make_uint2((unsigned int)s4.x | ((unsigned int)t4.x << 17), __float_as_uint(n4.x));
        recs[offs[d4.y] + p4.y] = make_uint2((unsigned int)s4.y | ((unsigned int)t4.y << 17), __float_as_uint(n4.y));
        recs[offs[d4.z] + p4.z] = make_uint2((unsigned int)s4.z | ((unsigned int)t4.z << 17), __float_as_uint(n4.z));
        recs[offs[d4.w] + p4.w] = make_uint2((unsigned int)s4.w | ((unsigned int)t4.w << 17), __float_as_uint(n4.w));
    }
}

// ---------- 4. fused gather + MFMA ----------
__device__ __forceinline__ void accum8(float* acc, uint4 hv, uint4 rv, float w) {
    float h0, h1, r0, r1;
    unpack2(hv.x, h0, h1); unpack2(rv.x, r0, r1);
    acc[0] += (h0 + r0) * w; acc[1] += (h1 + r1) * w;
    unpack2(hv.y, h0, h1); unpack2(rv.y, r0, r1);
    acc[2] += (h0 + r0) * w; acc[3] += (h1 + r1) * w;
    unpack2(hv.z, h0, h1); unpack2(rv.z, r0, r1);
    acc[4] += (h0 + r0) * w; acc[5] += (h1 + r1) * w;
    unpack2(hv.w, h0, h1); unpack2(rv.w, r0, r1);
    acc[6] += (h0 + r0) * w; acc[7] += (h1 + r1) * w;
}

// Per block: 64 rows, 4 waves, 16 rows/wave. Wave-local only -> no barriers.
// Each wave: 4 gather batches (4 dsts each, 16 lanes/dst, unroll-4 + recs
// prefetch) -> bf16 LDS tile -> 3-phase MFMA pipeline -> epilogue.
__global__ void __launch_bounds__(256, 4)
gather_mfma(const unsigned short* __restrict__ hb,
            const unsigned short* __restrict__ rb,
            const int* __restrict__ offs,
            const uint2* __restrict__ recs,
            const unsigned short* __restrict__ Wp,
            const float* __restrict__ bias,
            const float* __restrict__ his,
            float* __restrict__ out) {
    __shared__ unsigned short tile[4][16 * 136];   // per-wave 16x128 bf16, pad 8
    const int tid = threadIdx.x;
    const int wv = tid >> 6, lane = tid & 63;
    const int m0 = blockIdx.x * 64 + wv * 16;      // this wave's 16 rows
    if (m0 >= NUM_ENTS) return;                    // 100000 % 16 == 0: exact cover
    const int grp = lane >> 4, sub = lane & 15;    // gather roles
    const int rA = lane & 15, quad = lane >> 4;    // MFMA roles
    unsigned short* T = tile[wv];
    const unsigned short* hbp = hb + sub * 8;
    const unsigned short* rbp = rb + sub * 8;

    // ---- gather phase: 4 batches of 4 dsts (one dst per 16-lane group) ----
    #pragma unroll
    for (int b = 0; b < 4; ++b) {
        const int rloc = b * 4 + grp;
        const int d = m0 + rloc;
        const int beg = offs[d], end = offs[d + 1];
        float acc[8] = {0.f, 0.f, 0.f, 0.f, 0.f, 0.f, 0.f, 0.f};
        int i = beg;
        uint2 rcA[4];
        #pragma unroll
        for (int k = 0; k < 4; ++k) rcA[k] = recs[min(i + k, NUM_EDGES - 1)];
        while (__any(i < end)) {
            uint2 rcB[4];                          // prefetch next iteration's recs
            #pragma unroll
            for (int k = 0; k < 4; ++k) rcB[k] = recs[min(i + 4 + k, NUM_EDGES - 1)];
            uint4 hv[4], rv[4]; float w[4];
            #pragma unroll
            for (int k = 0; k < 4; ++k) {
                w[k] = (i + k) < end ? __uint_as_float(rcA[k].y) : 0.f;
                hv[k] = *(const uint4*)(hbp + (size_t)(rcA[k].x & 0x1FFFFu) * HD);
                rv[k] = *(const uint4*)(rbp + (size_t)(rcA[k].x >> 17) * HD);
            }
            #pragma unroll
            for (int k = 0; k < 4; ++k) accum8(acc, hv[k], rv[k], w[k]);
            #pragma unroll
            for (int k = 0; k < 4; ++k) rcA[k] = rcB[k];
            i += 4;
        }
        unsigned short* dT = T + rloc * 136 + sub * 8;
        *(ushort4*)(dT + 0) = make_ushort4(f2bf(acc[0]), f2bf(acc[1]), f2bf(acc[2]), f2bf(acc[3]));
        *(ushort4*)(dT + 4) = make_ushort4(f2bf(acc[4]), f2bf(acc[5]), f2bf(acc[6]), f2bf(acc[7]));
    }

    // ---- MFMA phase 1: A = S (LDS), B = Wn ; phase 2: A = h_norm (hb), B = Ws
    const bf16x8* WF = (const bf16x8*)Wp;
    f32x4 acc1[8];
    #pragma unroll
    for (int t = 0; t < 8; ++t) acc1[t] = (f32x4)0.f;

    #pragma unroll
    for (int ph = 0; ph < 2; ++ph) {
        bf16x8 a[4];
        if (ph == 0) {
            #pragma unroll
            for (int kt = 0; kt < 4; ++kt)
                a[kt] = *(const bf16x8*)(T + rA * 136 + kt * 32 + quad * 8);
        } else {
            const unsigned short* base = hb + (size_t)(m0 + rA) * HD + quad * 8;
            #pragma unroll
            for (int kt = 0; kt < 4; ++kt)
                a[kt] = *(const bf16x8*)(base + kt * 32);
        }
        #pragma unroll
        for (int t = 0; t < 8; ++t) {
            #pragma unroll
            for (int kt = 0; kt < 4; ++kt) {
                const bf16x8 bfr = WF[(size_t)(ph * 32 + t * 4 + kt) * 64 + lane];
                acc1[t] = __builtin_amdgcn_mfma_f32_16x16x32_bf16(a[kt], bfr, acc1[t], 0, 0, 0);
            }
        }
    }

    // rrelu (C layout: col = t*16 + rA, row = quad*4 + r)
    #pragma unroll
    for (int t = 0; t < 8; ++t)
        #pragma unroll
        for (int r = 0; r < 4; ++r)
            acc1[t][r] = acc1[t][r] >= 0.f ? acc1[t][r] : RRELU_SLOPE * acc1[t][r];

    // transpose hcur C-layout -> A-layout via wave-local LDS (bf16)
    #pragma unroll
    for (int t = 0; t < 8; ++t)
        #pragma unroll
        for (int r = 0; r < 4; ++r)
            T[(quad * 4 + r) * 136 + t * 16 + rA] = f2bf(acc1[t][r]);

    bf16x8 a3[4];
    #pragma unroll
    for (int kt = 0; kt < 4; ++kt)
        a3[kt] = *(const bf16x8*)(T + rA * 136 + kt * 32 + quad * 8);

    // phase 3 + epilogue fused per-t: one gate accumulator live at a time
    #pragma unroll
    for (int t = 0; t < 8; ++t) {
        const float bn = bias[t * 16 + rA];
        f32x4 c2 = (f32x4){bn, bn, bn, bn};
        #pragma unroll
        for (int kt = 0; kt < 4; ++kt) {
            const bf16x8 bfr = WF[(size_t)(64 + t * 4 + kt) * 64 + lane];
            c2 = __builtin_amdgcn_mfma_f32_16x16x32_bf16(a3[kt], bfr, c2, 0, 0, 0);
        }
        const int col = t * 16 + rA;
        #pragma unroll
        for (int r = 0; r < 4; ++r) {
            const size_t row = (size_t)(m0 + quad * 4 + r);
            const float g = 1.f / (1.f + __expf(-c2[r]));
            const float h = his[row * HD + col];
            out[row * HD + col] = g * acc1[t][r] + (1.f - g) * h;
        }
    }
}

// ---------- launch ----------
extern "C" void kernel_launch(void* const* d_in, const int* in_sizes, int n_in,
                              void* d_out, int out_size, void* d_ws, size_t ws_size,
                              hipStream_t stream) {
    const float* ent   = (const float*)d_in[0];
    const float* rel   = (const float*)d_in[1];
    const float* his   = (const float*)d_in[2];
    const float* Wn    = (const float*)d_in[3];
    const float* Ws    = (const float*)d_in[4];
    const float* Wt    = (const float*)d_in[5];
    const float* bias  = (const float*)d_in[6];
    const float* enorm = (const float*)d_in[7];
    const int* src = (const int*)d_in[8];
    const int* dst = (const int*)d_in[9];
    const int* ety = (const int*)d_in[10];
    float* out = (float*)d_out;

    // ws: hb 25.6MB | rb 256KB | Wp 96KB | cnt 400KB | offs 400KB | bsum 2KB |
    //     pos 8MB | recs 16MB   (~50.8MB; ws >= 51.6MB)
    char* p = (char*)d_ws;
    unsigned short* hb = (unsigned short*)p;  p += (size_t)NUM_ENTS * HD * 2;
    unsigned short* rb = (unsigned short*)p;  p += (size_t)NUM_RELS2 * HD * 2;
    unsigned short* Wp = (unsigned short*)p;  p += (size_t)96 * 64 * 8 * 2;
    int* cnt  = (int*)p;                      p += (size_t)NPAD * 4;
    int* offs = (int*)p;                      p += (size_t)NPAD * 4;
    int* bsum = (int*)p;                      p += 512 * 4;
    int* pos  = (int*)p;                      p += (size_t)NUM_EDGES * 4;
    uint2* recs = (uint2*)p;

    setup_kernel<<<SB_TOTAL, 256, 0, stream>>>(ent, rel, Wn, Ws, Wt, cnt, hb, rb, Wp);
    hist_kernel<<<EBLK, 256, 0, stream>>>(dst, cnt, pos);
    scan1_kernel<<<NBLK, 256, 0, stream>>>(cnt, offs, bsum);
    scan2_kernel<<<1, 512, 0, stream>>>(bsum);
    scan3_kernel<<<NBLK, 256, 0, stream>>>(offs, bsum);
    permute_kernel<<<EBLK, 256, 0, stream>>>(dst, src, ety, enorm, offs, pos, recs);
    gather_mfma<<<(NUM_ENTS + 63) / 64, 256, 0, stream>>>(hb, rb, offs, recs, Wp, bias, his, out);
}

// Round 3
// 423.151 us; speedup vs baseline: 1.2543x; 1.0233x over previous
//
#include <hip/hip_runtime.h>
#include <math.h>

#define NUM_ENTS   100000
#define HD         128
#define NUM_EDGES  2000000
#define NUM_RELS2  1000
#define RRELU_SLOPE 0.22916666666666666f
#define NBLK 391                 // ceil(100000/256)
#define NPAD (NBLK * 256)        // 100096 padded counter range
#define EQ4  (NUM_EDGES / 4)     // 500000 4-edge chunks
#define EBLK ((EQ4 + 255) / 256) // 1954 blocks for edge-chunk kernels

// setup_kernel section boundaries (exact covers, no remainders)
#define SB_CNT 391               // zero cnt: 391*256 = 100096
#define SB_HB  25000             // prep hb: 25000*4 rows = 100000
#define SB_RB  125               // relpack: 125*256 = 32000 float4 chunks
#define SB_WP  24                // wpack: 24*4 = 96 sub-blocks
#define SB_TOTAL (SB_CNT + SB_HB + SB_RB + SB_WP)   // 25540

typedef __attribute__((ext_vector_type(8))) short bf16x8;
typedef __attribute__((ext_vector_type(4))) float f32x4;

// ---------- bf16 helpers ----------
__device__ __forceinline__ float bf2f(unsigned short h) {
    union { unsigned int u; float f; } v;
    v.u = ((unsigned int)h) << 16;
    return v.f;
}
__device__ __forceinline__ void unpack2(unsigned int u, float& lo, float& hi) {
    union { unsigned int u; float f; } a, b;
    a.u = u << 16;          // low ushort = element c
    b.u = u & 0xffff0000u;  // high ushort = element c+1
    lo = a.f; hi = b.f;
}
__device__ __forceinline__ unsigned short f2bf(float f) {
    union { float f; unsigned int u; } v; v.f = f;
    unsigned int r = 0x7fffu + ((v.u >> 16) & 1u);  // RNE
    return (unsigned short)((v.u + r) >> 16);
}

// ---------- 1. setup: zero cnt | hb = bf16(l2norm(ent)) | rb | Wp ----------
__global__ void __launch_bounds__(256)
setup_kernel(const float* __restrict__ ent, const float* __restrict__ rel,
             const float* __restrict__ Wn, const float* __restrict__ Ws,
             const float* __restrict__ Wt,
             int* __restrict__ cnt, unsigned short* __restrict__ hb,
             unsigned short* __restrict__ rb, unsigned short* __restrict__ Wp) {
    const int bid = blockIdx.x, tid = threadIdx.x;
    if (bid < SB_CNT) {                                   // zero cnt
        cnt[bid * 256 + tid] = 0;
    } else if (bid < SB_CNT + SB_HB) {                    // hb
        const int row = (bid - SB_CNT) * 4 + (tid >> 6);
        const int lane = tid & 63;
        const float2 v = *(const float2*)(ent + (size_t)row * HD + lane * 2);
        float ss = v.x * v.x + v.y * v.y;
        #pragma unroll
        for (int m = 1; m < 64; m <<= 1) ss += __shfl_xor(ss, m, 64);
        const float inv = 1.0f / fmaxf(sqrtf(ss), 1e-12f);
        const unsigned int o = (unsigned int)f2bf(v.x * inv) |
                               ((unsigned int)f2bf(v.y * inv) << 16);
        *(unsigned int*)(hb + (size_t)row * HD + lane * 2) = o;
    } else if (bid < SB_CNT + SB_HB + SB_RB) {            // rb
        const int i = (bid - SB_CNT - SB_HB) * 256 + tid;
        const float4 v = ((const float4*)rel)[i];
        ushort4 o;
        o.x = f2bf(v.x); o.y = f2bf(v.y); o.z = f2bf(v.z); o.w = f2bf(v.w);
        ((ushort4*)rb)[i] = o;
    } else {                                              // Wp
        const int blk = (bid - SB_CNT - SB_HB - SB_RB) * 4 + (tid >> 6);
        const int lane = tid & 63;
        const int w = blk >> 5, rem = blk & 31, t = rem >> 2, kt = rem & 3;
        const float* W = (w == 0) ? Wn : (w == 1) ? Ws : Wt;
        const int n  = t * 16 + (lane & 15);
        const int k0 = kt * 32 + (lane >> 4) * 8;
        unsigned short tmp[8];
        #pragma unroll
        for (int j = 0; j < 8; ++j) tmp[j] = f2bf(W[(size_t)(k0 + j) * HD + n]);
        unsigned short* d = Wp + ((size_t)blk * 64 + lane) * 8;
        *(ushort4*)(d + 0) = make_ushort4(tmp[0], tmp[1], tmp[2], tmp[3]);
        *(ushort4*)(d + 4) = make_ushort4(tmp[4], tmp[5], tmp[6], tmp[7]);
    }
}

// ---------- 2. histogram + within-bucket position (int4-vectorized) ----------
// Atomic returns live HERE (fire -> store pos). R1 lesson: putting the atomic
// return on the permute scatter path costs ~110us of latency stall.
__global__ void __launch_bounds__(256)
hist_kernel(const int* __restrict__ dst, int* __restrict__ cnt, int* __restrict__ pos) {
    const int i = blockIdx.x * 256 + threadIdx.x;
    if (i < EQ4) {
        const int4 d4 = ((const int4*)dst)[i];
        int4 p4;
        p4.x = atomicAdd(&cnt[d4.x], 1);
        p4.y = atomicAdd(&cnt[d4.y], 1);
        p4.z = atomicAdd(&cnt[d4.z], 1);
        p4.w = atomicAdd(&cnt[d4.w], 1);
        ((int4*)pos)[i] = p4;          // contiguous 16B store
    }
}

__global__ void __launch_bounds__(256)
scan1_kernel(const int* __restrict__ cnt, int* __restrict__ offs, int* __restrict__ bsum) {
    __shared__ int tmp[256];
    const int t = threadIdx.x;
    const int i = blockIdx.x * 256 + t;
    const int v = cnt[i];
    tmp[t] = v;
    __syncthreads();
    #pragma unroll
    for (int d = 1; d < 256; d <<= 1) {
        const int a = (t >= d) ? tmp[t - d] : 0;
        __syncthreads();
        tmp[t] += a;
        __syncthreads();
    }
    offs[i] = tmp[t] - v;
    if (t == 255) bsum[blockIdx.x] = tmp[255];
}

__global__ void __launch_bounds__(512)
scan2_kernel(int* __restrict__ bsum) {
    __shared__ int tmp[512];
    const int t = threadIdx.x;
    const int v = (t < NBLK) ? bsum[t] : 0;
    tmp[t] = v;
    __syncthreads();
    #pragma unroll
    for (int d = 1; d < 512; d <<= 1) {
        const int a = (t >= d) ? tmp[t - d] : 0;
        __syncthreads();
        tmp[t] += a;
        __syncthreads();
    }
    if (t < NBLK) bsum[t] = tmp[t] - v;
}

__global__ void __launch_bounds__(256)
scan3_kernel(int* __restrict__ offs, const int* __restrict__ bsum) {
    const int i = blockIdx.x * 256 + threadIdx.x;
    offs[i] += bsum[blockIdx.x];
}

// ---------- 3. permute: pure scatter, plain loads only (no atomics) ----------
__global__ void __launch_bounds__(256)
permute_kernel(const int* __restrict__ dst, const int* __restrict__ src,
               const int* __restrict__ ety, const float* __restrict__ enorm,
               const int* __restrict__ offs, const int* __restrict__ pos,
               uint2* __restrict__ recs) {
    const int i = blockIdx.x * 256 + threadIdx.x;
    if (i < EQ4) {
        const int4 d4 = ((const int4*)dst)[i];
        const int4 s4 = ((const int4*)src)[i];
        const int4 t4 = ((const int4*)ety)[i];
        const float4 n4 = ((const float4*)enorm)[i];
        const int4 p4 = ((const int4*)pos)[i];
        recs[offs[d4.x] + p4.x] = make_uint2((unsigned int)s4.x | ((unsigned int)t4.x << 17), __float_as_uint(n4.x));
        recs[offs[d4.y] + p4.y] = make_uint2((unsigned int)s4.y | ((unsigned int)t4.y << 17), __float_as_uint(n4.y));
        recs[offs[d4.z] + p4.z] = make_uint2((unsigned int)s4.z | ((unsigned int)t4.z << 17), __float_as_uint(n4.z));
        recs[offs[d4.w] + p4.w] = make_uint2((unsigned int)s4.w | ((unsigned int)t4.w << 17), __float_as_uint(n4.w));
    }
}

// ---------- 4. fused gather + MFMA, 16 rows/block ----------
__device__ __forceinline__ void accum8(float* acc, uint4 hv, uint4 rv, float w) {
    float h0, h1, r0, r1;
    unpack2(hv.x, h0, h1); unpack2(rv.x, r0, r1);
    acc[0] += (h0 + r0) * w; acc[1] += (h1 + r1) * w;
    unpack2(hv.y, h0, h1); unpack2(rv.y, r0, r1);
    acc[2] += (h0 + r0) * w; acc[3] += (h1 + r1) * w;
    unpack2(hv.z, h0, h1); unpack2(rv.z, r0, r1);
    acc[4] += (h0 + r0) * w; acc[5] += (h1 + r1) * w;
    unpack2(hv.w, h0, h1); unpack2(rv.w, r0, r1);
    acc[6] += (h0 + r0) * w; acc[7] += (h1 + r1) * w;
}

// Block: 256 threads, 16 rows. Gather: 16 groups x 16 lanes, ALL dsts in
// parallel (single batch -> 6250 blocks, fine-grained tail; R2 showed the
// 64-row/4-serial-batch geometry ran at 32% occupancy, 2.5 TB/s).
// MFMA: 4 waves split the 8 col-tiles (2 each) over one shared LDS tile.
__global__ void __launch_bounds__(256, 4)
gather_mfma(const unsigned short* __restrict__ hb,
            const unsigned short* __restrict__ rb,
            const int* __restrict__ offs,
            const uint2* __restrict__ recs,
            const unsigned short* __restrict__ Wp,
            const float* __restrict__ bias,
            const float* __restrict__ his,
            float* __restrict__ out) {
    __shared__ unsigned short T[16 * 136];         // 16x128 bf16 tile, pad 8
    const int tid = threadIdx.x;
    const int m0 = blockIdx.x * 16;                // 100000/16 = 6250 exact
    const int grp = tid >> 4, sub = tid & 15;      // gather roles
    const int wv = tid >> 6, lane = tid & 63;
    const int rA = lane & 15, quad = lane >> 4;    // MFMA roles
    const unsigned short* hbp = hb + sub * 8;
    const unsigned short* rbp = rb + sub * 8;

    // ---- gather: one dst per group, 16 dsts fully parallel ----
    {
        const int d = m0 + grp;
        const int beg = offs[d], end = offs[d + 1];
        float acc[8] = {0.f, 0.f, 0.f, 0.f, 0.f, 0.f, 0.f, 0.f};
        int i = beg;
        uint2 rcA[4];
        #pragma unroll
        for (int k = 0; k < 4; ++k) rcA[k] = recs[min(i + k, NUM_EDGES - 1)];
        while (__any(i < end)) {
            uint2 rcB[4];                          // prefetch next iteration's recs
            #pragma unroll
            for (int k = 0; k < 4; ++k) rcB[k] = recs[min(i + 4 + k, NUM_EDGES - 1)];
            uint4 hv[4], rv[4]; float w[4];
            #pragma unroll
            for (int k = 0; k < 4; ++k) {
                w[k] = (i + k) < end ? __uint_as_float(rcA[k].y) : 0.f;
                hv[k] = *(const uint4*)(hbp + (size_t)(rcA[k].x & 0x1FFFFu) * HD);
                rv[k] = *(const uint4*)(rbp + (size_t)(rcA[k].x >> 17) * HD);
            }
            #pragma unroll
            for (int k = 0; k < 4; ++k) accum8(acc, hv[k], rv[k], w[k]);
            #pragma unroll
            for (int k = 0; k < 4; ++k) rcA[k] = rcB[k];
            i += 4;
        }
        unsigned short* dT = T + grp * 136 + sub * 8;
        *(ushort4*)(dT + 0) = make_ushort4(f2bf(acc[0]), f2bf(acc[1]), f2bf(acc[2]), f2bf(acc[3]));
        *(ushort4*)(dT + 4) = make_ushort4(f2bf(acc[4]), f2bf(acc[5]), f2bf(acc[6]), f2bf(acc[7]));
    }
    __syncthreads();

    // ---- MFMA: wave wv owns col-tiles t = wv*2 + tt ----
    const bf16x8* WF = (const bf16x8*)Wp;
    bf16x8 a1[4], a2[4];
    #pragma unroll
    for (int kt = 0; kt < 4; ++kt)
        a1[kt] = *(const bf16x8*)(T + rA * 136 + kt * 32 + quad * 8);
    {
        const unsigned short* base = hb + (size_t)(m0 + rA) * HD + quad * 8;
        #pragma unroll
        for (int kt = 0; kt < 4; ++kt)
            a2[kt] = *(const bf16x8*)(base + kt * 32);
    }

    f32x4 acc1[2];
    #pragma unroll
    for (int tt = 0; tt < 2; ++tt) acc1[tt] = (f32x4)0.f;

    #pragma unroll
    for (int tt = 0; tt < 2; ++tt) {
        const int t = wv * 2 + tt;
        #pragma unroll
        for (int kt = 0; kt < 4; ++kt) {             // phase 1: S @ Wn
            const bf16x8 bfr = WF[(size_t)(t * 4 + kt) * 64 + lane];
            acc1[tt] = __builtin_amdgcn_mfma_f32_16x16x32_bf16(a1[kt], bfr, acc1[tt], 0, 0, 0);
        }
        #pragma unroll
        for (int kt = 0; kt < 4; ++kt) {             // phase 2: h @ Ws
            const bf16x8 bfr = WF[(size_t)(32 + t * 4 + kt) * 64 + lane];
            acc1[tt] = __builtin_amdgcn_mfma_f32_16x16x32_bf16(a2[kt], bfr, acc1[tt], 0, 0, 0);
        }
    }

    // rrelu (C layout: col = t*16 + rA, row = quad*4 + r)
    #pragma unroll
    for (int tt = 0; tt < 2; ++tt)
        #pragma unroll
        for (int r = 0; r < 4; ++r)
            acc1[tt][r] = acc1[tt][r] >= 0.f ? acc1[tt][r] : RRELU_SLOPE * acc1[tt][r];

    __syncthreads();                                 // all a1 reads of T done
    // transpose hcur C-layout -> A-layout into T (each wave its 32 cols)
    #pragma unroll
    for (int tt = 0; tt < 2; ++tt)
        #pragma unroll
        for (int r = 0; r < 4; ++r)
            T[(quad * 4 + r) * 136 + (wv * 2 + tt) * 16 + rA] = f2bf(acc1[tt][r]);
    __syncthreads();

    bf16x8 a3[4];
    #pragma unroll
    for (int kt = 0; kt < 4; ++kt)
        a3[kt] = *(const bf16x8*)(T + rA * 136 + kt * 32 + quad * 8);

    // phase 3 + epilogue per col-tile
    #pragma unroll
    for (int tt = 0; tt < 2; ++tt) {
        const int t = wv * 2 + tt;
        const float bn = bias[t * 16 + rA];
        f32x4 c2 = (f32x4){bn, bn, bn, bn};
        #pragma unroll
        for (int kt = 0; kt < 4; ++kt) {
            const bf16x8 bfr = WF[(size_t)(64 + t * 4 + kt) * 64 + lane];
            c2 = __builtin_amdgcn_mfma_f32_16x16x32_bf16(a3[kt], bfr, c2, 0, 0, 0);
        }
        const int col = t * 16 + rA;
        #pragma unroll
        for (int r = 0; r < 4; ++r) {
            const size_t row = (size_t)(m0 + quad * 4 + r);
            const float g = 1.f / (1.f + __expf(-c2[r]));
            const float h = his[row * HD + col];
            out[row * HD + col] = g * acc1[tt][r] + (1.f - g) * h;
        }
    }
}

// ---------- launch ----------
extern "C" void kernel_launch(void* const* d_in, const int* in_sizes, int n_in,
                              void* d_out, int out_size, void* d_ws, size_t ws_size,
                              hipStream_t stream) {
    const float* ent   = (const float*)d_in[0];
    const float* rel   = (const float*)d_in[1];
    const float* his   = (const float*)d_in[2];
    const float* Wn    = (const float*)d_in[3];
    const float* Ws    = (const float*)d_in[4];
    const float* Wt    = (const float*)d_in[5];
    const float* bias  = (const float*)d_in[6];
    const float* enorm = (const float*)d_in[7];
    const int* src = (const int*)d_in[8];
    const int* dst = (const int*)d_in[9];
    const int* ety = (const int*)d_in[10];
    float* out = (float*)d_out;

    // ws: hb 25.6MB | rb 256KB | Wp 96KB | cnt 400KB | offs 400KB | bsum 2KB |
    //     pos 8MB | recs 16MB   (~50.8MB; ws >= 51.6MB)
    char* p = (char*)d_ws;
    unsigned short* hb = (unsigned short*)p;  p += (size_t)NUM_ENTS * HD * 2;
    unsigned short* rb = (unsigned short*)p;  p += (size_t)NUM_RELS2 * HD * 2;
    unsigned short* Wp = (unsigned short*)p;  p += (size_t)96 * 64 * 8 * 2;
    int* cnt  = (int*)p;                      p += (size_t)NPAD * 4;
    int* offs = (int*)p;                      p += (size_t)NPAD * 4;
    int* bsum = (int*)p;                      p += 512 * 4;
    int* pos  = (int*)p;                      p += (size_t)NUM_EDGES * 4;
    uint2* recs = (uint2*)p;

    setup_kernel<<<SB_TOTAL, 256, 0, stream>>>(ent, rel, Wn, Ws, Wt, cnt, hb, rb, Wp);
    hist_kernel<<<EBLK, 256, 0, stream>>>(dst, cnt, pos);
    scan1_kernel<<<NBLK, 256, 0, stream>>>(cnt, offs, bsum);
    scan2_kernel<<<1, 512, 0, stream>>>(bsum);
    scan3_kernel<<<NBLK, 256, 0, stream>>>(offs, bsum);
    permute_kernel<<<EBLK, 256, 0, stream>>>(dst, src, ety, enorm, offs, pos, recs);
    gather_mfma<<<NUM_ENTS / 16, 256, 0, stream>>>(hb, rb, offs, recs, Wp, bias, his, out);
}

// Round 4
// 411.432 us; speedup vs baseline: 1.2901x; 1.0285x over previous
//
#include <hip/hip_runtime.h>
#include <math.h>

#define NUM_ENTS   100000
#define HD         128
#define NUM_EDGES  2000000
#define NUM_RELS2  1000
#define RRELU_SLOPE 0.22916666666666666f
#define NBLK 391                 // ceil(100000/256)
#define NPAD (NBLK * 256)        // 100096 padded counter range
#define EQ4  (NUM_EDGES / 4)     // 500000 4-edge chunks
#define EBLK ((EQ4 + 255) / 256) // 1954 blocks, 1 chunk/thread
#define PBLK ((EQ4 + 511) / 512) // 977 blocks, 2 chunks/thread (permute)

// merged setup_kernel section boundaries (hist FIRST: long-latency atomics
// start earliest and overlap the BW-bound hb/rb/Wp sections)
#define SB_HIST EBLK             // 1954: edge histogram, int4/thread
#define SB_HB   25000            // hb: 25000*4 rows = 100000
#define SB_RB   125              // relpack: 125*256 = 32000 float4 chunks
#define SB_WP   24               // wpack: 24*4 = 96 sub-blocks
#define SB_TOTAL (SB_HIST + SB_HB + SB_RB + SB_WP)   // 27103

typedef __attribute__((ext_vector_type(8))) short bf16x8;
typedef __attribute__((ext_vector_type(4))) float f32x4;

// ---------- bf16 helpers ----------
__device__ __forceinline__ float bf2f(unsigned short h) {
    union { unsigned int u; float f; } v;
    v.u = ((unsigned int)h) << 16;
    return v.f;
}
__device__ __forceinline__ void unpack2(unsigned int u, float& lo, float& hi) {
    union { unsigned int u; float f; } a, b;
    a.u = u << 16;          // low ushort = element c
    b.u = u & 0xffff0000u;  // high ushort = element c+1
    lo = a.f; hi = b.f;
}
__device__ __forceinline__ unsigned short f2bf(float f) {
    union { float f; unsigned int u; } v; v.f = f;
    unsigned int r = 0x7fffu + ((v.u >> 16) & 1u);  // RNE
    return (unsigned short)((v.u + r) >> 16);
}

// ---------- 1. setup+hist: hist | hb = bf16(l2norm(ent)) | rb | Wp ----------
// cnt is pre-zeroed by hipMemsetAsync before this launch (stream-ordered),
// so the hist section can run concurrently with the other sections.
// Atomic returns live HERE (fire -> store pos). R1 lesson: putting the atomic
// return on the permute scatter path costs ~110us of latency stall.
__global__ void __launch_bounds__(256)
setup_kernel(const float* __restrict__ ent, const float* __restrict__ rel,
             const float* __restrict__ Wn, const float* __restrict__ Ws,
             const float* __restrict__ Wt, const int* __restrict__ dst,
             int* __restrict__ cnt, int* __restrict__ pos,
             unsigned short* __restrict__ hb,
             unsigned short* __restrict__ rb, unsigned short* __restrict__ Wp) {
    const int bid = blockIdx.x, tid = threadIdx.x;
    if (bid < SB_HIST) {                                  // hist + pos
        const int i = bid * 256 + tid;
        if (i < EQ4) {
            const int4 d4 = ((const int4*)dst)[i];
            int4 p4;
            p4.x = atomicAdd(&cnt[d4.x], 1);
            p4.y = atomicAdd(&cnt[d4.y], 1);
            p4.z = atomicAdd(&cnt[d4.z], 1);
            p4.w = atomicAdd(&cnt[d4.w], 1);
            ((int4*)pos)[i] = p4;          // contiguous 16B store
        }
    } else if (bid < SB_HIST + SB_HB) {                   // hb
        const int row = (bid - SB_HIST) * 4 + (tid >> 6);
        const int lane = tid & 63;
        const float2 v = *(const float2*)(ent + (size_t)row * HD + lane * 2);
        float ss = v.x * v.x + v.y * v.y;
        #pragma unroll
        for (int m = 1; m < 64; m <<= 1) ss += __shfl_xor(ss, m, 64);
        const float inv = 1.0f / fmaxf(sqrtf(ss), 1e-12f);
        const unsigned int o = (unsigned int)f2bf(v.x * inv) |
                               ((unsigned int)f2bf(v.y * inv) << 16);
        *(unsigned int*)(hb + (size_t)row * HD + lane * 2) = o;
    } else if (bid < SB_HIST + SB_HB + SB_RB) {           // rb
        const int i = (bid - SB_HIST - SB_HB) * 256 + tid;
        const float4 v = ((const float4*)rel)[i];
        ushort4 o;
        o.x = f2bf(v.x); o.y = f2bf(v.y); o.z = f2bf(v.z); o.w = f2bf(v.w);
        ((ushort4*)rb)[i] = o;
    } else {                                              // Wp
        const int blk = (bid - SB_HIST - SB_HB - SB_RB) * 4 + (tid >> 6);
        const int lane = tid & 63;
        const int w = blk >> 5, rem = blk & 31, t = rem >> 2, kt = rem & 3;
        const float* W = (w == 0) ? Wn : (w == 1) ? Ws : Wt;
        const int n  = t * 16 + (lane & 15);
        const int k0 = kt * 32 + (lane >> 4) * 8;
        unsigned short tmp[8];
        #pragma unroll
        for (int j = 0; j < 8; ++j) tmp[j] = f2bf(W[(size_t)(k0 + j) * HD + n]);
        unsigned short* d = Wp + ((size_t)blk * 64 + lane) * 8;
        *(ushort4*)(d + 0) = make_ushort4(tmp[0], tmp[1], tmp[2], tmp[3]);
        *(ushort4*)(d + 4) = make_ushort4(tmp[4], tmp[5], tmp[6], tmp[7]);
    }
}

__global__ void __launch_bounds__(256)
scan1_kernel(const int* __restrict__ cnt, int* __restrict__ offs, int* __restrict__ bsum) {
    __shared__ int tmp[256];
    const int t = threadIdx.x;
    const int i = blockIdx.x * 256 + t;
    const int v = cnt[i];
    tmp[t] = v;
    __syncthreads();
    #pragma unroll
    for (int d = 1; d < 256; d <<= 1) {
        const int a = (t >= d) ? tmp[t - d] : 0;
        __syncthreads();
        tmp[t] += a;
        __syncthreads();
    }
    offs[i] = tmp[t] - v;
    if (t == 255) bsum[blockIdx.x] = tmp[255];
}

__global__ void __launch_bounds__(512)
scan2_kernel(int* __restrict__ bsum) {
    __shared__ int tmp[512];
    const int t = threadIdx.x;
    const int v = (t < NBLK) ? bsum[t] : 0;
    tmp[t] = v;
    __syncthreads();
    #pragma unroll
    for (int d = 1; d < 512; d <<= 1) {
        const int a = (t >= d) ? tmp[t - d] : 0;
        __syncthreads();
        tmp[t] += a;
        __syncthreads();
    }
    if (t < NBLK) bsum[t] = tmp[t] - v;
}

__global__ void __launch_bounds__(256)
scan3_kernel(int* __restrict__ offs, const int* __restrict__ bsum) {
    const int i = blockIdx.x * 256 + threadIdx.x;
    offs[i] += bsum[blockIdx.x];
}

// ---------- 3. permute: pure scatter, plain loads only (no atomics) ----------
// 2 coalesced chunk-passes per thread for scatter MLP.
__global__ void __launch_bounds__(256)
permute_kernel(const int* __restrict__ dst, const int* __restrict__ src,
               const int* __restrict__ ety, const float* __restrict__ enorm,
               const int* __restrict__ offs, const int* __restrict__ pos,
               uint2* __restrict__ recs) {
    #pragma unroll
    for (int u = 0; u < 2; ++u) {
        const int i = blockIdx.x * 512 + u * 256 + threadIdx.x;
        if (i < EQ4) {
            const int4 d4 = ((const int4*)dst)[i];
            const int4 s4 = ((const int4*)src)[i];
            const int4 t4 = ((const int4*)ety)[i];
            const float4 n4 = ((const float4*)enorm)[i];
            const int4 p4 = ((const int4*)pos)[i];
            recs[offs[d4.x] + p4.x] = make_uint2((unsigned int)s4.x | ((unsigned int)t4.x << 17), __float_as_uint(n4.x));
            recs[offs[d4.y] + p4.y] = make_uint2((unsigned int)s4.y | ((unsigned int)t4.y << 17), __float_as_uint(n4.y));
            recs[offs[d4.z] + p4.z] = make_uint2((unsigned int)s4.z | ((unsigned int)t4.z << 17), __float_as_uint(n4.z));
            recs[offs[d4.w] + p4.w] = make_uint2((unsigned int)s4.w | ((unsigned int)t4.w << 17), __float_as_uint(n4.w));
        }
    }
}

// ---------- 4. fused gather + MFMA, 16 rows/block ----------
__device__ __forceinline__ void accum8(float* acc, uint4 hv, uint4 rv, float w) {
    float h0, h1, r0, r1;
    unpack2(hv.x, h0, h1); unpack2(rv.x, r0, r1);
    acc[0] += (h0 + r0) * w; acc[1] += (h1 + r1) * w;
    unpack2(hv.y, h0, h1); unpack2(rv.y, r0, r1);
    acc[2] += (h0 + r0) * w; acc[3] += (h1 + r1) * w;
    unpack2(hv.z, h0, h1); unpack2(rv.z, r0, r1);
    acc[4] += (h0 + r0) * w; acc[5] += (h1 + r1) * w;
    unpack2(hv.w, h0, h1); unpack2(rv.w, r0, r1);
    acc[6] += (h0 + r0) * w; acc[7] += (h1 + r1) * w;
}

// Block: 256 threads, 16 rows. Gather: 16 groups x 16 lanes, all dsts in
// parallel. R4: natural per-group loop (condition uniform within each
// 16-lane group) replaces the wave-wide __any loop — finished groups stop
// issuing clamped dummy row-loads (was ~32% dead traffic at deg~Poisson(20)).
// MFMA: 4 waves split the 8 col-tiles (2 each) over one shared LDS tile.
__global__ void __launch_bounds__(256, 4)
gather_mfma(const unsigned short* __restrict__ hb,
            const unsigned short* __restrict__ rb,
            const int* __restrict__ offs,
            const uint2* __restrict__ recs,
            const unsigned short* __restrict__ Wp,
            const float* __restrict__ bias,
            const float* __restrict__ his,
            float* __restrict__ out) {
    __shared__ unsigned short T[16 * 136];         // 16x128 bf16 tile, pad 8
    const int tid = threadIdx.x;
    const int m0 = blockIdx.x * 16;                // 100000/16 = 6250 exact
    const int grp = tid >> 4, sub = tid & 15;      // gather roles
    const int wv = tid >> 6, lane = tid & 63;
    const int rA = lane & 15, quad = lane >> 4;    // MFMA roles
    const unsigned short* hbp = hb + sub * 8;
    const unsigned short* rbp = rb + sub * 8;

    // ---- gather: one dst per group, 16 dsts fully parallel ----
    {
        const int d = m0 + grp;
        const int beg = offs[d], end = offs[d + 1];
        float acc[8] = {0.f, 0.f, 0.f, 0.f, 0.f, 0.f, 0.f, 0.f};
        int i = beg;
        if (i < end) {                             // group-uniform divergence
            uint2 rcA[4];
            #pragma unroll
            for (int k = 0; k < 4; ++k) rcA[k] = recs[min(i + k, NUM_EDGES - 1)];
            for (; i < end; i += 4) {
                uint2 rcB[4];                      // prefetch next iteration's recs
                #pragma unroll
                for (int k = 0; k < 4; ++k) rcB[k] = recs[min(i + 4 + k, NUM_EDGES - 1)];
                uint4 hv[4], rv[4]; float w[4];
                #pragma unroll
                for (int k = 0; k < 4; ++k) {
                    w[k] = (i + k) < end ? __uint_as_float(rcA[k].y) : 0.f;
                    hv[k] = *(const uint4*)(hbp + (size_t)(rcA[k].x & 0x1FFFFu) * HD);
                    rv[k] = *(const uint4*)(rbp + (size_t)(rcA[k].x >> 17) * HD);
                }
                #pragma unroll
                for (int k = 0; k < 4; ++k) accum8(acc, hv[k], rv[k], w[k]);
                #pragma unroll
                for (int k = 0; k < 4; ++k) rcA[k] = rcB[k];
            }
        }
        unsigned short* dT = T + grp * 136 + sub * 8;
        *(ushort4*)(dT + 0) = make_ushort4(f2bf(acc[0]), f2bf(acc[1]), f2bf(acc[2]), f2bf(acc[3]));
        *(ushort4*)(dT + 4) = make_ushort4(f2bf(acc[4]), f2bf(acc[5]), f2bf(acc[6]), f2bf(acc[7]));
    }
    __syncthreads();

    // ---- MFMA: wave wv owns col-tiles t = wv*2 + tt ----
    const bf16x8* WF = (const bf16x8*)Wp;
    bf16x8 a1[4], a2[4];
    #pragma unroll
    for (int kt = 0; kt < 4; ++kt)
        a1[kt] = *(const bf16x8*)(T + rA * 136 + kt * 32 + quad * 8);
    {
        const unsigned short* base = hb + (size_t)(m0 + rA) * HD + quad * 8;
        #pragma unroll
        for (int kt = 0; kt < 4; ++kt)
            a2[kt] = *(const bf16x8*)(base + kt * 32);
    }

    f32x4 acc1[2];
    #pragma unroll
    for (int tt = 0; tt < 2; ++tt) acc1[tt] = (f32x4)0.f;

    #pragma unroll
    for (int tt = 0; tt < 2; ++tt) {
        const int t = wv * 2 + tt;
        #pragma unroll
        for (int kt = 0; kt < 4; ++kt) {             // phase 1: S @ Wn
            const bf16x8 bfr = WF[(size_t)(t * 4 + kt) * 64 + lane];
            acc1[tt] = __builtin_amdgcn_mfma_f32_16x16x32_bf16(a1[kt], bfr, acc1[tt], 0, 0, 0);
        }
        #pragma unroll
        for (int kt = 0; kt < 4; ++kt) {             // phase 2: h @ Ws
            const bf16x8 bfr = WF[(size_t)(32 + t * 4 + kt) * 64 + lane];
            acc1[tt] = __builtin_amdgcn_mfma_f32_16x16x32_bf16(a2[kt], bfr, acc1[tt], 0, 0, 0);
        }
    }

    // rrelu (C layout: col = t*16 + rA, row = quad*4 + r)
    #pragma unroll
    for (int tt = 0; tt < 2; ++tt)
        #pragma unroll
        for (int r = 0; r < 4; ++r)
            acc1[tt][r] = acc1[tt][r] >= 0.f ? acc1[tt][r] : RRELU_SLOPE * acc1[tt][r];

    __syncthreads();                                 // all a1 reads of T done
    // transpose hcur C-layout -> A-layout into T (each wave its 32 cols)
    #pragma unroll
    for (int tt = 0; tt < 2; ++tt)
        #pragma unroll
        for (int r = 0; r < 4; ++r)
            T[(quad * 4 + r) * 136 + (wv * 2 + tt) * 16 + rA] = f2bf(acc1[tt][r]);
    __syncthreads();

    bf16x8 a3[4];
    #pragma unroll
    for (int kt = 0; kt < 4; ++kt)
        a3[kt] = *(const bf16x8*)(T + rA * 136 + kt * 32 + quad * 8);

    // phase 3 + epilogue per col-tile
    #pragma unroll
    for (int tt = 0; tt < 2; ++tt) {
        const int t = wv * 2 + tt;
        const float bn = bias[t * 16 + rA];
        f32x4 c2 = (f32x4){bn, bn, bn, bn};
        #pragma unroll
        for (int kt = 0; kt < 4; ++kt) {
            const bf16x8 bfr = WF[(size_t)(64 + t * 4 + kt) * 64 + lane];
            c2 = __builtin_amdgcn_mfma_f32_16x16x32_bf16(a3[kt], bfr, c2, 0, 0, 0);
        }
        const int col = t * 16 + rA;
        #pragma unroll
        for (int r = 0; r < 4; ++r) {
            const size_t row = (size_t)(m0 + quad * 4 + r);
            const float g = 1.f / (1.f + __expf(-c2[r]));
            const float h = his[row * HD + col];
            out[row * HD + col] = g * acc1[tt][r] + (1.f - g) * h;
        }
    }
}

// ---------- launch ----------
extern "C" void kernel_launch(void* const* d_in, const int* in_sizes, int n_in,
                              void* d_out, int out_size, void* d_ws, size_t ws_size,
                              hipStream_t stream) {
    const float* ent   = (const float*)d_in[0];
    const float* rel   = (const float*)d_in[1];
    const float* his   = (const float*)d_in[2];
    const float* Wn    = (const float*)d_in[3];
    const float* Ws    = (const float*)d_in[4];
    const float* Wt    = (const float*)d_in[5];
    const float* bias  = (const float*)d_in[6];
    const float* enorm = (const float*)d_in[7];
    const int* src = (const int*)d_in[8];
    const int* dst = (const int*)d_in[9];
    const int* ety = (const int*)d_in[10];
    float* out = (float*)d_out;

    // ws: hb 25.6MB | rb 256KB | Wp 96KB | cnt 400KB | offs 400KB | bsum 2KB |
    //     pos 8MB | recs 16MB   (~50.8MB; ws >= 51.6MB)
    char* p = (char*)d_ws;
    unsigned short* hb = (unsigned short*)p;  p += (size_t)NUM_ENTS * HD * 2;
    unsigned short* rb = (unsigned short*)p;  p += (size_t)NUM_RELS2 * HD * 2;
    unsigned short* Wp = (unsigned short*)p;  p += (size_t)96 * 64 * 8 * 2;
    int* cnt  = (int*)p;                      p += (size_t)NPAD * 4;
    int* offs = (int*)p;                      p += (size_t)NPAD * 4;
    int* bsum = (int*)p;                      p += 512 * 4;
    int* pos  = (int*)p;                      p += (size_t)NUM_EDGES * 4;
    uint2* recs = (uint2*)p;

    hipMemsetAsync(cnt, 0, (size_t)NPAD * 4, stream);   // async, capture-safe
    setup_kernel<<<SB_TOTAL, 256, 0, stream>>>(ent, rel, Wn, Ws, Wt, dst, cnt, pos, hb, rb, Wp);
    scan1_kernel<<<NBLK, 256, 0, stream>>>(cnt, offs, bsum);
    scan2_kernel<<<1, 512, 0, stream>>>(bsum);
    scan3_kernel<<<NBLK, 256, 0, stream>>>(offs, bsum);
    permute_kernel<<<PBLK, 256, 0, stream>>>(dst, src, ety, enorm, offs, pos, recs);
    gather_mfma<<<NUM_ENTS / 16, 256, 0, stream>>>(hb, rb, offs, recs, Wp, bias, his, out);
}